// Round 3
// baseline (55948.364 us; speedup 1.0000x reference)
//
#include <hip/hip_runtime.h>
#include <hip/hip_bf16.h>
#include <cstdint>
#include <cstddef>

// Problem constants
#define TT 512
#define BB 32
#define DD 1024
#define HH 1024
#define SS 512

typedef _Float16 f16x8 __attribute__((ext_vector_type(8)));
typedef _Float16 f16x4 __attribute__((ext_vector_type(4)));
typedef _Float16 f16x2 __attribute__((ext_vector_type(2)));
typedef float f32x4 __attribute__((ext_vector_type(4)));

__device__ __forceinline__ float sigm(float x) { return 1.0f / (1.0f + __expf(-x)); }
__device__ __forceinline__ float tanh_fast(float x) {
    return 1.0f - 2.0f / (__expf(2.0f * x) + 1.0f);  // saturates, no inf/inf
}
// load 8 contiguous fp32, round to fp16 MFMA fragment
__device__ __forceinline__ f16x8 cvt8(const float* __restrict__ p) {
    float4 u = *(const float4*)p;
    float4 v = *(const float4*)(p + 4);
    f16x8 r;
    r[0] = (_Float16)u.x; r[1] = (_Float16)u.y; r[2] = (_Float16)u.z; r[3] = (_Float16)u.w;
    r[4] = (_Float16)v.x; r[5] = (_Float16)v.y; r[6] = (_Float16)v.z; r[7] = (_Float16)v.w;
    return r;
}

// ---------------------------------------------------------------------------
// staging: fp32 -> fp16 copy (grid-stride, float4 -> f16x4)
// ---------------------------------------------------------------------------
__global__ __launch_bounds__(256) void k_cvt(const float* __restrict__ s,
                                             _Float16* __restrict__ d, int n4) {
    for (int i = blockIdx.x * blockDim.x + threadIdx.x; i < n4; i += gridDim.x * blockDim.x) {
        float4 v = ((const float4*)s)[i];
        f16x4 h;
        h[0] = (_Float16)v.x; h[1] = (_Float16)v.y;
        h[2] = (_Float16)v.z; h[3] = (_Float16)v.w;
        ((f16x4*)d)[i] = h;
    }
}

__global__ void k_bias(const float* __restrict__ bih, const float* __restrict__ bhh,
                       float* __restrict__ bsum) {
    const int i = blockIdx.x * blockDim.x + threadIdx.x;
    if (i < 4 * HH) bsum[i] = bih[i] + bhh[i];
}

__global__ void k_init(const float* __restrict__ c0, float* __restrict__ cbuf) {
    const int i = blockIdx.x * blockDim.x + threadIdx.x;
    if (i < BB * HH) cbuf[i] = c0[i];
}

__global__ void k_fin(const float* __restrict__ lasth, const float* __restrict__ cbuf,
                      float* __restrict__ hT, float* __restrict__ cT) {
    const int i = blockIdx.x * blockDim.x + threadIdx.x;
    if (i < BB * HH) {
        hT[i] = lasth[i];
        cT[i] = cbuf[i];
    }
}

// ---------------------------------------------------------------------------
// K_pre: gx[m,n] = sum_d x[m,d]*Wih[n,d], fp32 in, fp16 out. 64x64 tile/wave.
// ---------------------------------------------------------------------------
__global__ __launch_bounds__(256) void k_pre(const float* __restrict__ x,
                                             const float* __restrict__ Wih,
                                             _Float16* __restrict__ gx) {
    const int wave = (blockIdx.x * blockDim.x + threadIdx.x) >> 6;
    const int lane = threadIdx.x & 63;
    const int m0 = (wave >> 6) * 64, n0 = (wave & 63) * 64;
    const int lm = lane & 15, q8 = (lane >> 4) * 8;

    f32x4 acc[4][4];
    #pragma unroll
    for (int i = 0; i < 4; ++i)
        #pragma unroll
        for (int j = 0; j < 4; ++j) acc[i][j] = (f32x4)0.0f;

    for (int k0 = 0; k0 < DD; k0 += 32) {
        f16x8 a[4], b[4];
        #pragma unroll
        for (int i = 0; i < 4; ++i)
            a[i] = cvt8(x + (size_t)(m0 + i * 16 + lm) * DD + k0 + q8);
        #pragma unroll
        for (int j = 0; j < 4; ++j)
            b[j] = cvt8(Wih + (size_t)(n0 + j * 16 + lm) * DD + k0 + q8);
        #pragma unroll
        for (int i = 0; i < 4; ++i)
            #pragma unroll
            for (int j = 0; j < 4; ++j)
                acc[i][j] = __builtin_amdgcn_mfma_f32_16x16x32_f16(a[i], b[j], acc[i][j], 0, 0, 0);
    }
    const int rq = (lane >> 4) * 4;
    #pragma unroll
    for (int i = 0; i < 4; ++i)
        #pragma unroll
        for (int j = 0; j < 4; ++j)
            #pragma unroll
            for (int r = 0; r < 4; ++r)
                gx[(size_t)(m0 + i * 16 + rq + r) * (4 * HH) + n0 + j * 16 + lm] =
                    (_Float16)acc[i][j][r];
}

// ---------------------------------------------------------------------------
// K1: gates = [gx_t or xt@Wih^T] + hprev@Whh^T + bsum ; LSTM cell.
// grid = 128 x 64. One wave: 16 batch rows x 16 h-cols, all 4 gates.
// hprev is fp32 (exact carry) -> fp16 in-register.
// ---------------------------------------------------------------------------
__global__ __launch_bounds__(64) void k_step1(const float* __restrict__ hprev,
                                              const _Float16* __restrict__ Whh_h,
                                              const float* __restrict__ Whh_f,
                                              const _Float16* __restrict__ gx_t,
                                              const float* __restrict__ xt_f,
                                              const _Float16* __restrict__ Wih_h,
                                              const float* __restrict__ Wih_f,
                                              const float* __restrict__ bsum,
                                              float* __restrict__ cbuf,
                                              float* __restrict__ hy,
                                              int use_pre, int staged) {
    const int wave = blockIdx.x;
    const int lane = threadIdx.x;
    const int m0 = (wave >> 6) * 16;
    const int j0 = (wave & 63) * 16;
    const int lm = lane & 15, q8 = (lane >> 4) * 8;

    f32x4 acc[4];
    #pragma unroll
    for (int q = 0; q < 4; ++q) acc[q] = (f32x4)0.0f;

    const float* arow = hprev + (size_t)(m0 + lm) * HH;
    if (staged) {
        for (int k0 = 0; k0 < HH; k0 += 32) {
            f16x8 a = cvt8(arow + k0 + q8);
            #pragma unroll
            for (int q = 0; q < 4; ++q) {
                f16x8 b = *(const f16x8*)(Whh_h + (size_t)(q * HH + j0 + lm) * HH + k0 + q8);
                acc[q] = __builtin_amdgcn_mfma_f32_16x16x32_f16(a, b, acc[q], 0, 0, 0);
            }
        }
    } else {
        for (int k0 = 0; k0 < HH; k0 += 32) {
            f16x8 a = cvt8(arow + k0 + q8);
            #pragma unroll
            for (int q = 0; q < 4; ++q) {
                f16x8 b = cvt8(Whh_f + (size_t)(q * HH + j0 + lm) * HH + k0 + q8);
                acc[q] = __builtin_amdgcn_mfma_f32_16x16x32_f16(a, b, acc[q], 0, 0, 0);
            }
        }
    }
    if (!use_pre) {
        const float* xrow = xt_f + (size_t)(m0 + lm) * DD;
        if (staged) {
            for (int k0 = 0; k0 < DD; k0 += 32) {
                f16x8 a = cvt8(xrow + k0 + q8);
                #pragma unroll
                for (int q = 0; q < 4; ++q) {
                    f16x8 b = *(const f16x8*)(Wih_h + (size_t)(q * HH + j0 + lm) * DD + k0 + q8);
                    acc[q] = __builtin_amdgcn_mfma_f32_16x16x32_f16(a, b, acc[q], 0, 0, 0);
                }
            }
        } else {
            for (int k0 = 0; k0 < DD; k0 += 32) {
                f16x8 a = cvt8(xrow + k0 + q8);
                #pragma unroll
                for (int q = 0; q < 4; ++q) {
                    f16x8 b = cvt8(Wih_f + (size_t)(q * HH + j0 + lm) * DD + k0 + q8);
                    acc[q] = __builtin_amdgcn_mfma_f32_16x16x32_f16(a, b, acc[q], 0, 0, 0);
                }
            }
        }
    }
    const int rq = (lane >> 4) * 4;
    const int j = j0 + lm;
    const float bs_i = bsum[j], bs_f = bsum[HH + j], bs_g = bsum[2 * HH + j], bs_o = bsum[3 * HH + j];
    #pragma unroll
    for (int r = 0; r < 4; ++r) {
        const int b = m0 + rq + r;
        float gi = acc[0][r] + bs_i, gf = acc[1][r] + bs_f;
        float gg = acc[2][r] + bs_g, go = acc[3][r] + bs_o;
        if (use_pre) {
            const _Float16* g = gx_t + (size_t)b * (4 * HH);
            gi += (float)g[j];
            gf += (float)g[HH + j];
            gg += (float)g[2 * HH + j];
            go += (float)g[3 * HH + j];
        }
        const float cprev = cbuf[b * HH + j];
        const float cy = sigm(gf) * cprev + sigm(gi) * tanh_fast(gg);
        const float hv = sigm(go) * tanh_fast(cy);
        cbuf[b * HH + j] = cy;
        hy[b * HH + j] = hv;
    }
}

// ---------------------------------------------------------------------------
// K2: target = hy @ W_in^T (fp32 out). grid = 128 x 64.
// ---------------------------------------------------------------------------
__global__ __launch_bounds__(64) void k_target(const float* __restrict__ hy,
                                               const _Float16* __restrict__ Win_h,
                                               const float* __restrict__ Win_f,
                                               float* __restrict__ target,
                                               int staged) {
    const int wave = blockIdx.x;
    const int lane = threadIdx.x;
    const int m0 = (wave >> 6) * 16;
    const int j0 = (wave & 63) * 16;
    const int lm = lane & 15, q8 = (lane >> 4) * 8;

    f32x4 acc = (f32x4)0.0f;
    const float* arow = hy + (size_t)(m0 + lm) * HH;
    if (staged) {
        for (int k0 = 0; k0 < HH; k0 += 32) {
            f16x8 a = cvt8(arow + k0 + q8);
            f16x8 b = *(const f16x8*)(Win_h + (size_t)(j0 + lm) * HH + k0 + q8);
            acc = __builtin_amdgcn_mfma_f32_16x16x32_f16(a, b, acc, 0, 0, 0);
        }
    } else {
        for (int k0 = 0; k0 < HH; k0 += 32) {
            f16x8 a = cvt8(arow + k0 + q8);
            f16x8 b = cvt8(Win_f + (size_t)(j0 + lm) * HH + k0 + q8);
            acc = __builtin_amdgcn_mfma_f32_16x16x32_f16(a, b, acc, 0, 0, 0);
        }
    }
    const int rq = (lane >> 4) * 4;
    const int j = j0 + lm;
    #pragma unroll
    for (int r = 0; r < 4; ++r)
        target[(m0 + rq + r) * HH + j] = acc[r];
}

// ---------------------------------------------------------------------------
// K3: scores[b,s] = sum_h ctx[s,b,h]*target[b,h]. One wave per (b,s).
// ---------------------------------------------------------------------------
__global__ __launch_bounds__(256) void k_scores(const _Float16* __restrict__ ctx_h,
                                                const float* __restrict__ ctx_f,
                                                const float* __restrict__ target,
                                                float* __restrict__ scores, int staged) {
    const int idx = (blockIdx.x * blockDim.x + threadIdx.x) >> 6;  // b*512+s
    const int lane = threadIdx.x & 63;
    const int b = idx >> 9;
    const int s = idx & 511;
    const float* trow = target + b * HH + lane * 16;
    float4 t0 = *(const float4*)(trow);
    float4 t1 = *(const float4*)(trow + 4);
    float4 t2 = *(const float4*)(trow + 8);
    float4 t3 = *(const float4*)(trow + 12);
    float sum = 0.0f;
    if (staged) {
        const _Float16* crow = ctx_h + ((size_t)s * BB + b) * HH + lane * 16;
        f16x8 c0 = *(const f16x8*)(crow);
        f16x8 c1 = *(const f16x8*)(crow + 8);
        sum += (float)c0[0] * t0.x + (float)c0[1] * t0.y + (float)c0[2] * t0.z + (float)c0[3] * t0.w;
        sum += (float)c0[4] * t1.x + (float)c0[5] * t1.y + (float)c0[6] * t1.z + (float)c0[7] * t1.w;
        sum += (float)c1[0] * t2.x + (float)c1[1] * t2.y + (float)c1[2] * t2.z + (float)c1[3] * t2.w;
        sum += (float)c1[4] * t3.x + (float)c1[5] * t3.y + (float)c1[6] * t3.z + (float)c1[7] * t3.w;
    } else {
        const float* crow = ctx_f + ((size_t)s * BB + b) * HH + lane * 16;
        float4 c0 = *(const float4*)(crow);
        float4 c1 = *(const float4*)(crow + 4);
        float4 c2 = *(const float4*)(crow + 8);
        float4 c3 = *(const float4*)(crow + 12);
        sum += c0.x * t0.x + c0.y * t0.y + c0.z * t0.z + c0.w * t0.w;
        sum += c1.x * t1.x + c1.y * t1.y + c1.z * t1.z + c1.w * t1.w;
        sum += c2.x * t2.x + c2.y * t2.y + c2.z * t2.z + c2.w * t2.w;
        sum += c3.x * t3.x + c3.y * t3.y + c3.z * t3.z + c3.w * t3.w;
    }
    #pragma unroll
    for (int off = 32; off > 0; off >>= 1) sum += __shfl_down(sum, off, 64);
    if (lane == 0) scores[b * SS + s] = sum;
}

// ---------------------------------------------------------------------------
// K4: softmax over s + wc[b,h] = sum_s attn[b,s]*ctx[s,b,h]. grid = 64 x 256.
// ---------------------------------------------------------------------------
__global__ __launch_bounds__(256) void k_attn(const _Float16* __restrict__ ctx_h,
                                              const float* __restrict__ ctx_f,
                                              const float* __restrict__ scores,
                                              float* __restrict__ wc, int staged) {
    __shared__ float sm[SS];
    __shared__ float red[256];
    const int b = blockIdx.x >> 1;
    const int hc = blockIdx.x & 1;
    const int t = threadIdx.x;

    const float v0 = scores[b * SS + t];
    const float v1 = scores[b * SS + 256 + t];
    red[t] = fmaxf(v0, v1);
    __syncthreads();
    for (int o = 128; o > 0; o >>= 1) {
        if (t < o) red[t] = fmaxf(red[t], red[t + o]);
        __syncthreads();
    }
    const float mx = red[0];
    __syncthreads();
    const float e0 = __expf(v0 - mx);
    const float e1 = __expf(v1 - mx);
    sm[t] = e0;
    sm[t + 256] = e1;
    red[t] = e0 + e1;
    __syncthreads();
    for (int o = 128; o > 0; o >>= 1) {
        if (t < o) red[t] += red[t + o];
        __syncthreads();
    }
    const float inv = 1.0f / red[0];

    const int h = hc * 512 + t * 2;
    float a0 = 0.0f, a1 = 0.0f;
    if (staged) {
        const _Float16* cbase = ctx_h + (size_t)b * HH + h;
        #pragma unroll 8
        for (int s = 0; s < SS; ++s) {
            const float a = sm[s];
            const f16x2 u = *(const f16x2*)(cbase + (size_t)s * (BB * HH));
            a0 += a * (float)u[0];
            a1 += a * (float)u[1];
        }
    } else {
        const float* cbase = ctx_f + (size_t)b * HH + h;
        #pragma unroll 8
        for (int s = 0; s < SS; ++s) {
            const float a = sm[s];
            const float2 u = *(const float2*)(cbase + (size_t)s * (BB * HH));
            a0 += a * u.x;
            a1 += a * u.y;
        }
    }
    wc[b * HH + h] = a0 * inv;
    wc[b * HH + h + 1] = a1 * inv;
}

// ---------------------------------------------------------------------------
// K5: h_tilde = tanh([wc, hy] @ W_out^T) -> out_t (fp32, also next carry).
// ---------------------------------------------------------------------------
__global__ __launch_bounds__(64) void k_out(const float* __restrict__ wc,
                                            const float* __restrict__ hy,
                                            const _Float16* __restrict__ Wout_h,
                                            const float* __restrict__ Wout_f,
                                            float* __restrict__ out_t,
                                            int staged) {
    const int wave = blockIdx.x;
    const int lane = threadIdx.x;
    const int m0 = (wave >> 6) * 16;
    const int j0 = (wave & 63) * 16;
    const int lm = lane & 15, q8 = (lane >> 4) * 8;

    f32x4 acc = (f32x4)0.0f;
    const float* arow1 = wc + (size_t)(m0 + lm) * HH;
    const float* arow2 = hy + (size_t)(m0 + lm) * HH;
    if (staged) {
        const _Float16* brow = Wout_h + (size_t)(j0 + lm) * (2 * HH);
        for (int k0 = 0; k0 < HH; k0 += 32) {
            f16x8 a = cvt8(arow1 + k0 + q8);
            f16x8 b = *(const f16x8*)(brow + k0 + q8);
            acc = __builtin_amdgcn_mfma_f32_16x16x32_f16(a, b, acc, 0, 0, 0);
        }
        for (int k0 = 0; k0 < HH; k0 += 32) {
            f16x8 a = cvt8(arow2 + k0 + q8);
            f16x8 b = *(const f16x8*)(brow + HH + k0 + q8);
            acc = __builtin_amdgcn_mfma_f32_16x16x32_f16(a, b, acc, 0, 0, 0);
        }
    } else {
        const float* brow = Wout_f + (size_t)(j0 + lm) * (2 * HH);
        for (int k0 = 0; k0 < HH; k0 += 32) {
            f16x8 a = cvt8(arow1 + k0 + q8);
            f16x8 b = cvt8(brow + k0 + q8);
            acc = __builtin_amdgcn_mfma_f32_16x16x32_f16(a, b, acc, 0, 0, 0);
        }
        for (int k0 = 0; k0 < HH; k0 += 32) {
            f16x8 a = cvt8(arow2 + k0 + q8);
            f16x8 b = cvt8(brow + HH + k0 + q8);
            acc = __builtin_amdgcn_mfma_f32_16x16x32_f16(a, b, acc, 0, 0, 0);
        }
    }
    const int rq = (lane >> 4) * 4;
    const int j = j0 + lm;
    #pragma unroll
    for (int r = 0; r < 4; ++r)
        out_t[(m0 + rq + r) * HH + j] = tanh_fast(acc[r]);
}

extern "C" void kernel_launch(void* const* d_in, const int* in_sizes, int n_in,
                              void* d_out, int out_size, void* d_ws, size_t ws_size,
                              hipStream_t stream) {
    const float* x    = (const float*)d_in[0];
    const float* h0   = (const float*)d_in[1];
    const float* c0   = (const float*)d_in[2];
    const float* ctx  = (const float*)d_in[3];
    const float* Wih  = (const float*)d_in[4];
    const float* bih  = (const float*)d_in[5];
    const float* Whh  = (const float*)d_in[6];
    const float* bhh  = (const float*)d_in[7];
    const float* Win  = (const float*)d_in[8];
    const float* Wout = (const float*)d_in[9];
    float* out = (float*)d_out;

    char* ws = (char*)d_ws;
    // fp32 intermediates (always required, 592 KiB)
    float* cbuf   = (float*)(ws + 0);        // 131072
    float* hy     = (float*)(ws + 131072);   // 131072
    float* target = (float*)(ws + 262144);   // 131072
    float* scores = (float*)(ws + 393216);   //  65536
    float* wc     = (float*)(ws + 458752);   // 131072
    float* bsum   = (float*)(ws + 589824);   //  16384
    // staged fp16 copies
    _Float16* Whh_h  = (_Float16*)(ws + 606208);    //  8388608
    _Float16* Win_h  = (_Float16*)(ws + 8994816);   //  2097152
    _Float16* Wout_h = (_Float16*)(ws + 11091968);  //  4194304
    _Float16* Wih_h  = (_Float16*)(ws + 15286272);  //  8388608
    _Float16* ctx_h  = (_Float16*)(ws + 23674880);  // 33554432
    _Float16* gx     = (_Float16*)(ws + 57229312);  // 134217728

    const int staged  = (ws_size >= (size_t)57229312) ? 1 : 0;
    const int use_pre = (ws_size >= (size_t)191447040) ? 1 : 0;

    k_bias<<<16, 256, 0, stream>>>(bih, bhh, bsum);
    k_init<<<128, 256, 0, stream>>>(c0, cbuf);
    if (staged) {
        k_cvt<<<1024, 256, 0, stream>>>(Whh, Whh_h, 4 * HH * HH / 4);
        k_cvt<<<1024, 256, 0, stream>>>(Win, Win_h, HH * HH / 4);
        k_cvt<<<1024, 256, 0, stream>>>(Wout, Wout_h, 2 * HH * HH / 4);
        k_cvt<<<2048, 256, 0, stream>>>(ctx, ctx_h, SS * BB * HH / 4);
        if (!use_pre) k_cvt<<<1024, 256, 0, stream>>>(Wih, Wih_h, 4 * HH * DD / 4);
    }
    if (use_pre) k_pre<<<4096, 256, 0, stream>>>(x, Wih, gx);

    for (int t = 0; t < TT; ++t) {
        const float* hprev = (t == 0) ? h0 : (out + (size_t)(t - 1) * BB * HH);
        const _Float16* gx_t = gx + (size_t)t * BB * 4 * HH;
        const float* xt = x + (size_t)t * BB * DD;
        float* out_t = out + (size_t)t * BB * HH;

        k_step1<<<128, 64, 0, stream>>>(hprev, Whh_h, Whh, gx_t, xt, Wih_h, Wih,
                                        bsum, cbuf, hy, use_pre, staged);
        k_target<<<128, 64, 0, stream>>>(hy, Win_h, Win, target, staged);
        k_scores<<<4096, 256, 0, stream>>>(ctx_h, ctx, target, scores, staged);
        k_attn<<<64, 256, 0, stream>>>(ctx_h, ctx, scores, wc, staged);
        k_out<<<128, 64, 0, stream>>>(wc, hy, Wout_h, Wout, out_t, staged);
    }

    float* hT = out + (size_t)TT * BB * HH;
    float* cT = hT + BB * HH;
    k_fin<<<128, 256, 0, stream>>>(out + (size_t)(TT - 1) * BB * HH, cbuf, hT, cT);
}